// Round 5
// baseline (193.401 us; speedup 1.0000x reference)
//
#include <hip/hip_runtime.h>
#include <hip/hip_bf16.h>

// Problem constants
constexpr int B      = 16384;
constexpr int D_IN   = 1024;
constexpr int D_OUT  = 256;
constexpr int NCLS   = 1000;
constexpr int CPAD   = 1024;   // padded class count

// ---------------- workspace layout (byte offsets) ----------------
constexpr size_t OFF_S    = 0;                                   // CPAD*D_IN f32 (4 MB)
constexpr size_t OFF_Z    = OFF_S   + (size_t)CPAD * D_IN * 4;   // CPAD*D_OUT f32 (1 MB)
constexpr size_t OFF_T    = OFF_Z   + (size_t)CPAD * D_OUT * 4;  // D_IN f32
constexpr size_t OFF_CNT  = OFF_T   + (size_t)D_IN * 4;          // CPAD int
constexpr size_t OFF_OFFS = OFF_CNT + (size_t)CPAD * 4;          // CPAD int
constexpr size_t OFF_ROWL = OFF_OFFS+ (size_t)CPAD * 4;          // B int

typedef short bf16x8 __attribute__((ext_vector_type(8)));
typedef float f32x4  __attribute__((ext_vector_type(4)));

// LDS row stride (shorts) for 32-wide K tiles: 32 data + 8 pad -> frag reads 2-way (free)
constexpr int LSTR = 40;

// fp32 -> bf16 round-to-nearest-even
__device__ __forceinline__ unsigned short f2bf(float f) {
    unsigned int u = __float_as_uint(f);
    return (unsigned short)((u + 0x7FFFu + ((u >> 16) & 1u)) >> 16);
}

__device__ __forceinline__ void cvt8(const float4& a, const float4& b, unsigned short* dst) {
    union { unsigned short u[8]; bf16x8 v; } r;
    r.u[0] = f2bf(a.x); r.u[1] = f2bf(a.y); r.u[2] = f2bf(a.z); r.u[3] = f2bf(a.w);
    r.u[4] = f2bf(b.x); r.u[5] = f2bf(b.y); r.u[6] = f2bf(b.z); r.u[7] = f2bf(b.w);
    *(bf16x8*)dst = r.v;
}

// ---------------- fused label pipeline: zero T, hist, scan, scatter ----------------
__global__ __launch_bounds__(1024)
void label_kernel(const int* __restrict__ label,
                  float* __restrict__ T,
                  int* __restrict__ cnt_g,
                  int* __restrict__ offs_g,
                  int* __restrict__ rowlist) {
    __shared__ int bufA[1024];
    __shared__ int bufB[1024];
    __shared__ int cur[1024];
    const int t = threadIdx.x;

    T[t] = 0.f;          // zero grand-total accumulator (tsum atomics land here)
    bufA[t] = 0;
    __syncthreads();
    // histogram: 16 coalesced strided passes
#pragma unroll
    for (int i = 0; i < 16; ++i)
        atomicAdd(&bufA[label[i * 1024 + t]], 1);
    __syncthreads();
    const int v = bufA[t];
    cnt_g[t] = v;
    // Hillis-Steele inclusive scan, ping-pong
    int* src = bufA;
    int* dst = bufB;
    for (int off = 1; off < 1024; off <<= 1) {
        int sv = src[t];
        if (t >= off) sv += src[t - off];
        dst[t] = sv;
        __syncthreads();
        int* tmp = src; src = dst; dst = tmp;
    }
    const int excl = src[t] - v;
    offs_g[t] = excl;
    cur[t] = excl;
    __syncthreads();
    // scatter (counting sort of row ids)
#pragma unroll
    for (int i = 0; i < 16; ++i) {
        int idx = i * 1024 + t;
        int c = label[idx];
        int p = atomicAdd(&cur[c], 1);
        rowlist[p] = idx;
    }
}

// ---------------- per-class fp32 column sums of x (no atomics) ----------------
__global__ void segsum_kernel(const float* __restrict__ x,
                              const int* __restrict__ offs,
                              const int* __restrict__ cnt,
                              const int* __restrict__ rowlist,
                              float* __restrict__ s) {
    int c = blockIdx.x;            // 0..1023
    int col = threadIdx.x * 4;     // 256 threads * 4 cols = 1024
    float4 acc = {0.f, 0.f, 0.f, 0.f};
    if (c < NCLS) {
        int o = offs[c], n = cnt[c];
        int r = 0;
        for (; r + 4 <= n; r += 4) {
            int i0 = rowlist[o + r + 0];
            int i1 = rowlist[o + r + 1];
            int i2 = rowlist[o + r + 2];
            int i3 = rowlist[o + r + 3];
            float4 v0 = *(const float4*)(x + (size_t)i0 * D_IN + col);
            float4 v1 = *(const float4*)(x + (size_t)i1 * D_IN + col);
            float4 v2 = *(const float4*)(x + (size_t)i2 * D_IN + col);
            float4 v3 = *(const float4*)(x + (size_t)i3 * D_IN + col);
            acc.x += (v0.x + v1.x) + (v2.x + v3.x);
            acc.y += (v0.y + v1.y) + (v2.y + v3.y);
            acc.z += (v0.z + v1.z) + (v2.z + v3.z);
            acc.w += (v0.w + v1.w) + (v2.w + v3.w);
        }
        for (; r < n; ++r) {
            int i0 = rowlist[o + r];
            float4 v = *(const float4*)(x + (size_t)i0 * D_IN + col);
            acc.x += v.x; acc.y += v.y; acc.z += v.z; acc.w += v.w;
        }
    }
    *(float4*)(s + (size_t)c * D_IN + col) = acc;
}

// T = column-sum of s; 8 blocks -> only 8 atomics per address
__global__ void tsum_kernel(const float* __restrict__ s, float* __restrict__ T) {
    int col = threadIdx.x * 4;
    int c0 = blockIdx.x * (CPAD / 8);
    float4 acc = {0.f, 0.f, 0.f, 0.f};
    for (int c = 0; c < CPAD / 8; ++c) {
        float4 v = *(const float4*)(s + (size_t)(c0 + c) * D_IN + col);
        acc.x += v.x; acc.y += v.y; acc.z += v.z; acc.w += v.w;
    }
    atomicAdd(&T[col + 0], acc.x);
    atomicAdd(&T[col + 1], acc.y);
    atomicAdd(&T[col + 2], acc.z);
    atomicAdd(&T[col + 3], acc.w);
}

// ---------------- Z[c] = ((T - s_c)/d_c) @ W2^T + b2 ; 64x64 tile, BK=32 ----------------
__global__ __launch_bounds__(256)
void meanz_kernel(const float* __restrict__ s,
                  const float* __restrict__ T,
                  const int* __restrict__ cnt,
                  const float* __restrict__ W2,
                  const float* __restrict__ b2,
                  float* __restrict__ Z) {
    __shared__ unsigned short As[64 * LSTR];
    __shared__ unsigned short Bs[64 * LSTR];

    const int tid  = threadIdx.x;
    const int wave = tid >> 6;
    const int lane = tid & 63;
    const int quad = lane >> 4;
    const int l16  = lane & 15;
    const int bm   = blockIdx.x * 64;   // class base
    const int bn   = blockIdx.y * 64;   // out-col base
    const int wm   = (wave >> 1) * 32;
    const int wn   = (wave & 1) * 32;

    const int arow = tid >> 2;          // 0..63
    const int akc  = (tid & 3) * 8;     // 0,8,16,24

    const int cls = bm + arow;
    const int d   = B - cnt[cls];
    const float scale = (d > 0) ? 1.f / (float)d : 0.f;
    const float* sp = s  + (size_t)cls * D_IN + akc;
    const float* wp = W2 + (size_t)(bn + arow) * D_IN + akc;

    f32x4 acc[2][2] = {};

    for (int k0 = 0; k0 < D_IN; k0 += 32) {
        float4 s0 = *(const float4*)(sp + k0);
        float4 s1 = *(const float4*)(sp + k0 + 4);
        float4 t0 = *(const float4*)(T + k0 + akc);
        float4 t1 = *(const float4*)(T + k0 + akc + 4);
        float4 w0 = *(const float4*)(wp + k0);
        float4 w1 = *(const float4*)(wp + k0 + 4);
        __syncthreads();
        float4 m0 = {(t0.x - s0.x) * scale, (t0.y - s0.y) * scale,
                     (t0.z - s0.z) * scale, (t0.w - s0.w) * scale};
        float4 m1 = {(t1.x - s1.x) * scale, (t1.y - s1.y) * scale,
                     (t1.z - s1.z) * scale, (t1.w - s1.w) * scale};
        cvt8(m0, m1, As + arow * LSTR + akc);
        cvt8(w0, w1, Bs + arow * LSTR + akc);
        __syncthreads();

        bf16x8 af[2], bfr[2];
#pragma unroll
        for (int t = 0; t < 2; ++t) {
            af[t]  = *(const bf16x8*)&As[(wm + t * 16 + l16) * LSTR + quad * 8];
            bfr[t] = *(const bf16x8*)&Bs[(wn + t * 16 + l16) * LSTR + quad * 8];
        }
#pragma unroll
        for (int i = 0; i < 2; ++i)
#pragma unroll
            for (int j = 0; j < 2; ++j)
                acc[i][j] = __builtin_amdgcn_mfma_f32_16x16x32_bf16(af[i], bfr[j], acc[i][j], 0, 0, 0);
    }

#pragma unroll
    for (int j = 0; j < 2; ++j) {
        const int n = bn + wn + j * 16 + l16;
        const float bias = b2[n];
#pragma unroll
        for (int i = 0; i < 2; ++i)
#pragma unroll
            for (int r = 0; r < 4; ++r) {
                const int c = bm + wm + i * 16 + quad * 4 + r;
                Z[(size_t)c * D_OUT + n] = acc[i][j][r] + bias;
            }
    }
}

// ---------------- out = x @ W1^T + b1 + Z[label] ; 64x64 tile, BK=32 ----------------
// grid (B/64, 4) = 1024 blocks -> 4 blocks/CU, inline fp32->bf16 for both A and B
__global__ __launch_bounds__(256, 4)
void gemm1_kernel(const float* __restrict__ x,
                  const float* __restrict__ W1,
                  const float* __restrict__ b1,
                  const float* __restrict__ Z,
                  const int* __restrict__ label,
                  float* __restrict__ out) {
    __shared__ unsigned short As[64 * LSTR];
    __shared__ unsigned short Bs[64 * LSTR];

    const int tid  = threadIdx.x;
    const int wave = tid >> 6;
    const int lane = tid & 63;
    const int quad = lane >> 4;
    const int l16  = lane & 15;
    const int bm   = blockIdx.x * 64;
    const int bn   = blockIdx.y * 64;
    const int wm   = (wave >> 1) * 32;
    const int wn   = (wave & 1) * 32;

    const int arow = tid >> 2;          // 0..63
    const int akc  = (tid & 3) * 8;     // 0,8,16,24
    const float* aptr = x  + (size_t)(bm + arow) * D_IN + akc;
    const float* bptr = W1 + (size_t)(bn + arow) * D_IN + akc;

    f32x4 acc[2][2] = {};

    for (int k0 = 0; k0 < D_IN; k0 += 32) {
        float4 a0 = *(const float4*)(aptr + k0);
        float4 a1 = *(const float4*)(aptr + k0 + 4);
        float4 b0 = *(const float4*)(bptr + k0);
        float4 b1v = *(const float4*)(bptr + k0 + 4);
        __syncthreads();   // previous iteration's frag reads complete
        cvt8(a0, a1, As + arow * LSTR + akc);
        cvt8(b0, b1v, Bs + arow * LSTR + akc);
        __syncthreads();

        bf16x8 af[2], bfr[2];
#pragma unroll
        for (int t = 0; t < 2; ++t) {
            af[t]  = *(const bf16x8*)&As[(wm + t * 16 + l16) * LSTR + quad * 8];
            bfr[t] = *(const bf16x8*)&Bs[(wn + t * 16 + l16) * LSTR + quad * 8];
        }
#pragma unroll
        for (int i = 0; i < 2; ++i)
#pragma unroll
            for (int j = 0; j < 2; ++j)
                acc[i][j] = __builtin_amdgcn_mfma_f32_16x16x32_bf16(af[i], bfr[j], acc[i][j], 0, 0, 0);
    }

    // epilogue: out[m][n] = acc + b1[n] + Z[label[m]][n]
    int zrow[2][4];
#pragma unroll
    for (int i = 0; i < 2; ++i)
#pragma unroll
        for (int r = 0; r < 4; ++r)
            zrow[i][r] = label[bm + wm + i * 16 + quad * 4 + r] * D_OUT;

#pragma unroll
    for (int j = 0; j < 2; ++j) {
        const int n = bn + wn + j * 16 + l16;
        const float bias = b1[n];
#pragma unroll
        for (int i = 0; i < 2; ++i)
#pragma unroll
            for (int r = 0; r < 4; ++r) {
                const int m = bm + wm + i * 16 + quad * 4 + r;
                out[(size_t)m * D_OUT + n] = acc[i][j][r] + bias + Z[zrow[i][r] + n];
            }
    }
}

// ---------------- launcher ----------------
extern "C" void kernel_launch(void* const* d_in, const int* in_sizes, int n_in,
                              void* d_out, int out_size, void* d_ws, size_t ws_size,
                              hipStream_t stream) {
    const float* x    = (const float*)d_in[0];
    const int*   lab  = (const int*)d_in[1];
    const float* W1_w = (const float*)d_in[2];
    const float* W1_b = (const float*)d_in[3];
    const float* W2_w = (const float*)d_in[4];
    const float* W2_b = (const float*)d_in[5];
    float* out = (float*)d_out;

    char* ws = (char*)d_ws;
    float* s   = (float*)(ws + OFF_S);
    float* Z   = (float*)(ws + OFF_Z);
    float* T   = (float*)(ws + OFF_T);
    int* cnt     = (int*)(ws + OFF_CNT);
    int* offs    = (int*)(ws + OFF_OFFS);
    int* rowlist = (int*)(ws + OFF_ROWL);

    // 1. fused label pipeline (also zeroes T)
    label_kernel<<<1, 1024, 0, stream>>>(lab, T, cnt, offs, rowlist);
    // 2. per-class fp32 sums
    segsum_kernel<<<CPAD, 256, 0, stream>>>(x, offs, cnt, rowlist, s);
    // 3. grand total (8-way contention only)
    tsum_kernel<<<8, 256, 0, stream>>>(s, T);
    // 4. Z table (inline W2 convert)
    dim3 zgrid(CPAD / 64, D_OUT / 64);
    meanz_kernel<<<zgrid, 256, 0, stream>>>(s, T, cnt, W2_w, W2_b, Z);
    // 5. main GEMM, 1024 blocks (inline W1 convert, fused bias + Z gather)
    dim3 ggrid(B / 64, D_OUT / 64);
    gemm1_kernel<<<ggrid, 256, 0, stream>>>(x, W1_w, W1_b, Z, lab, out);
}

// Round 6
// 193.006 us; speedup vs baseline: 1.0020x; 1.0020x over previous
//
#include <hip/hip_runtime.h>
#include <hip/hip_bf16.h>

// Problem constants
constexpr int B      = 16384;
constexpr int D_IN   = 1024;
constexpr int D_OUT  = 256;
constexpr int NCLS   = 1000;
constexpr int CPAD   = 1024;   // padded class count

// ---------------- workspace layout (byte offsets) ----------------
constexpr size_t OFF_S    = 0;                                   // CPAD*D_IN f32 (4 MB)
constexpr size_t OFF_Z    = OFF_S   + (size_t)CPAD * D_IN * 4;   // CPAD*D_OUT f32 (1 MB)
constexpr size_t OFF_T    = OFF_Z   + (size_t)CPAD * D_OUT * 4;  // D_IN f32
constexpr size_t OFF_CNT  = OFF_T   + (size_t)D_IN * 4;          // CPAD int
constexpr size_t OFF_OFFS = OFF_CNT + (size_t)CPAD * 4;          // CPAD int
constexpr size_t OFF_ROWL = OFF_OFFS+ (size_t)CPAD * 4;          // B int

typedef short bf16x8 __attribute__((ext_vector_type(8)));
typedef float f32x4  __attribute__((ext_vector_type(4)));

// LDS row stride (shorts): 32 data + 8 pad; 80B stride keeps 16B alignment,
// frag ds_read_b128 lands at worst 2-way bank aliasing (free per m136)
constexpr int LSTR = 40;

// fp32 -> bf16 round-to-nearest-even
__device__ __forceinline__ unsigned short f2bf(float f) {
    unsigned int u = __float_as_uint(f);
    return (unsigned short)((u + 0x7FFFu + ((u >> 16) & 1u)) >> 16);
}

__device__ __forceinline__ void cvt8(const float4& a, const float4& b, unsigned short* dst) {
    union { unsigned short u[8]; bf16x8 v; } r;
    r.u[0] = f2bf(a.x); r.u[1] = f2bf(a.y); r.u[2] = f2bf(a.z); r.u[3] = f2bf(a.w);
    r.u[4] = f2bf(b.x); r.u[5] = f2bf(b.y); r.u[6] = f2bf(b.z); r.u[7] = f2bf(b.w);
    *(bf16x8*)dst = r.v;
}

// ---------------- fused label pipeline: zero T, hist, scan, scatter ----------------
__global__ __launch_bounds__(1024)
void label_kernel(const int* __restrict__ label,
                  float* __restrict__ T,
                  int* __restrict__ cnt_g,
                  int* __restrict__ offs_g,
                  int* __restrict__ rowlist) {
    __shared__ int bufA[1024];
    __shared__ int bufB[1024];
    __shared__ int cur[1024];
    const int t = threadIdx.x;

    T[t] = 0.f;          // zero grand-total accumulator (tsum atomics land here)
    bufA[t] = 0;
    __syncthreads();
#pragma unroll
    for (int i = 0; i < 16; ++i)
        atomicAdd(&bufA[label[i * 1024 + t]], 1);
    __syncthreads();
    const int v = bufA[t];
    cnt_g[t] = v;
    int* src = bufA;
    int* dst = bufB;
    for (int off = 1; off < 1024; off <<= 1) {
        int sv = src[t];
        if (t >= off) sv += src[t - off];
        dst[t] = sv;
        __syncthreads();
        int* tmp = src; src = dst; dst = tmp;
    }
    const int excl = src[t] - v;
    offs_g[t] = excl;
    cur[t] = excl;
    __syncthreads();
#pragma unroll
    for (int i = 0; i < 16; ++i) {
        int idx = i * 1024 + t;
        int c = label[idx];
        int p = atomicAdd(&cur[c], 1);
        rowlist[p] = idx;
    }
}

// ---------------- per-class fp32 column sums of x (no atomics) ----------------
__global__ void segsum_kernel(const float* __restrict__ x,
                              const int* __restrict__ offs,
                              const int* __restrict__ cnt,
                              const int* __restrict__ rowlist,
                              float* __restrict__ s) {
    int c = blockIdx.x;            // 0..1023
    int col = threadIdx.x * 4;
    float4 acc = {0.f, 0.f, 0.f, 0.f};
    if (c < NCLS) {
        int o = offs[c], n = cnt[c];
        int r = 0;
        for (; r + 4 <= n; r += 4) {
            int i0 = rowlist[o + r + 0];
            int i1 = rowlist[o + r + 1];
            int i2 = rowlist[o + r + 2];
            int i3 = rowlist[o + r + 3];
            float4 v0 = *(const float4*)(x + (size_t)i0 * D_IN + col);
            float4 v1 = *(const float4*)(x + (size_t)i1 * D_IN + col);
            float4 v2 = *(const float4*)(x + (size_t)i2 * D_IN + col);
            float4 v3 = *(const float4*)(x + (size_t)i3 * D_IN + col);
            acc.x += (v0.x + v1.x) + (v2.x + v3.x);
            acc.y += (v0.y + v1.y) + (v2.y + v3.y);
            acc.z += (v0.z + v1.z) + (v2.z + v3.z);
            acc.w += (v0.w + v1.w) + (v2.w + v3.w);
        }
        for (; r < n; ++r) {
            int i0 = rowlist[o + r];
            float4 v = *(const float4*)(x + (size_t)i0 * D_IN + col);
            acc.x += v.x; acc.y += v.y; acc.z += v.z; acc.w += v.w;
        }
    }
    *(float4*)(s + (size_t)c * D_IN + col) = acc;
}

// T = column-sum of s; 64 blocks x 16 classes -> 64 atomics per address
__global__ void tsum_kernel(const float* __restrict__ s, float* __restrict__ T) {
    int col = threadIdx.x * 4;
    int c0 = blockIdx.x * 16;
    float4 acc = {0.f, 0.f, 0.f, 0.f};
#pragma unroll 4
    for (int c = 0; c < 16; ++c) {
        float4 v = *(const float4*)(s + (size_t)(c0 + c) * D_IN + col);
        acc.x += v.x; acc.y += v.y; acc.z += v.z; acc.w += v.w;
    }
    atomicAdd(&T[col + 0], acc.x);
    atomicAdd(&T[col + 1], acc.y);
    atomicAdd(&T[col + 2], acc.z);
    atomicAdd(&T[col + 3], acc.w);
}

// ---------------- Z[c] = ((T - s_c)/d_c) @ W2^T + b2 ; 64x64 tile, BK=32, prefetched ----
__global__ __launch_bounds__(256)
void meanz_kernel(const float* __restrict__ s,
                  const float* __restrict__ T,
                  const int* __restrict__ cnt,
                  const float* __restrict__ W2,
                  const float* __restrict__ b2,
                  float* __restrict__ Z) {
    __shared__ unsigned short As[64 * LSTR];
    __shared__ unsigned short Bs[64 * LSTR];

    const int tid  = threadIdx.x;
    const int wave = tid >> 6;
    const int lane = tid & 63;
    const int quad = lane >> 4;
    const int l16  = lane & 15;
    const int bm   = blockIdx.x * 64;   // class base
    const int bn   = blockIdx.y * 64;   // out-col base
    const int wm   = (wave >> 1) * 32;
    const int wn   = (wave & 1) * 32;

    const int arow = tid >> 2;          // 0..63
    const int akc  = (tid & 3) * 8;     // 0,8,16,24

    const int cls = bm + arow;
    const int d   = B - cnt[cls];
    const float scale = (d > 0) ? 1.f / (float)d : 0.f;
    const float* sp = s  + (size_t)cls * D_IN + akc;
    const float* wp = W2 + (size_t)(bn + arow) * D_IN + akc;
    const float* tp = T + akc;

    f32x4 acc[2][2] = {};

    // prefetch k0 = 0
    float4 s0 = *(const float4*)(sp);
    float4 s1 = *(const float4*)(sp + 4);
    float4 t0 = *(const float4*)(tp);
    float4 t1 = *(const float4*)(tp + 4);
    float4 w0 = *(const float4*)(wp);
    float4 w1 = *(const float4*)(wp + 4);

    for (int k0 = 0; k0 < D_IN; k0 += 32) {
        __syncthreads();   // previous iteration's frag reads complete
        float4 m0 = {(t0.x - s0.x) * scale, (t0.y - s0.y) * scale,
                     (t0.z - s0.z) * scale, (t0.w - s0.w) * scale};
        float4 m1 = {(t1.x - s1.x) * scale, (t1.y - s1.y) * scale,
                     (t1.z - s1.z) * scale, (t1.w - s1.w) * scale};
        cvt8(m0, m1, As + arow * LSTR + akc);
        cvt8(w0, w1, Bs + arow * LSTR + akc);
        __syncthreads();
        if (k0 + 32 < D_IN) {   // issue next iteration's loads before MFMA
            s0 = *(const float4*)(sp + k0 + 32);
            s1 = *(const float4*)(sp + k0 + 36);
            t0 = *(const float4*)(tp + k0 + 32);
            t1 = *(const float4*)(tp + k0 + 36);
            w0 = *(const float4*)(wp + k0 + 32);
            w1 = *(const float4*)(wp + k0 + 36);
        }

        bf16x8 af[2], bfr[2];
#pragma unroll
        for (int t = 0; t < 2; ++t) {
            af[t]  = *(const bf16x8*)&As[(wm + t * 16 + l16) * LSTR + quad * 8];
            bfr[t] = *(const bf16x8*)&Bs[(wn + t * 16 + l16) * LSTR + quad * 8];
        }
#pragma unroll
        for (int i = 0; i < 2; ++i)
#pragma unroll
            for (int j = 0; j < 2; ++j)
                acc[i][j] = __builtin_amdgcn_mfma_f32_16x16x32_bf16(af[i], bfr[j], acc[i][j], 0, 0, 0);
    }

#pragma unroll
    for (int j = 0; j < 2; ++j) {
        const int n = bn + wn + j * 16 + l16;
        const float bias = b2[n];
#pragma unroll
        for (int i = 0; i < 2; ++i)
#pragma unroll
            for (int r = 0; r < 4; ++r) {
                const int c = bm + wm + i * 16 + quad * 4 + r;
                Z[(size_t)c * D_OUT + n] = acc[i][j][r] + bias;
            }
    }
}

// ---------------- out = x @ W1^T + b1 + Z[label] ; 64x64 tile, BK=32, prefetched --------
__global__ __launch_bounds__(256, 4)
void gemm1_kernel(const float* __restrict__ x,
                  const float* __restrict__ W1,
                  const float* __restrict__ b1,
                  const float* __restrict__ Z,
                  const int* __restrict__ label,
                  float* __restrict__ out) {
    __shared__ unsigned short As[64 * LSTR];
    __shared__ unsigned short Bs[64 * LSTR];

    const int tid  = threadIdx.x;
    const int wave = tid >> 6;
    const int lane = tid & 63;
    const int quad = lane >> 4;
    const int l16  = lane & 15;
    const int bm   = blockIdx.x * 64;
    const int bn   = blockIdx.y * 64;
    const int wm   = (wave >> 1) * 32;
    const int wn   = (wave & 1) * 32;

    const int arow = tid >> 2;          // 0..63
    const int akc  = (tid & 3) * 8;     // 0,8,16,24
    const float* aptr = x  + (size_t)(bm + arow) * D_IN + akc;
    const float* bptr = W1 + (size_t)(bn + arow) * D_IN + akc;

    f32x4 acc[2][2] = {};

    // prefetch k0 = 0
    float4 a0 = *(const float4*)(aptr);
    float4 a1 = *(const float4*)(aptr + 4);
    float4 b0 = *(const float4*)(bptr);
    float4 b1v = *(const float4*)(bptr + 4);

    for (int k0 = 0; k0 < D_IN; k0 += 32) {
        __syncthreads();   // previous iteration's frag reads complete
        cvt8(a0, a1, As + arow * LSTR + akc);
        cvt8(b0, b1v, Bs + arow * LSTR + akc);
        __syncthreads();
        if (k0 + 32 < D_IN) {   // issue next iteration's loads before MFMA
            a0  = *(const float4*)(aptr + k0 + 32);
            a1  = *(const float4*)(aptr + k0 + 36);
            b0  = *(const float4*)(bptr + k0 + 32);
            b1v = *(const float4*)(bptr + k0 + 36);
        }

        bf16x8 af[2], bfr[2];
#pragma unroll
        for (int t = 0; t < 2; ++t) {
            af[t]  = *(const bf16x8*)&As[(wm + t * 16 + l16) * LSTR + quad * 8];
            bfr[t] = *(const bf16x8*)&Bs[(wn + t * 16 + l16) * LSTR + quad * 8];
        }
#pragma unroll
        for (int i = 0; i < 2; ++i)
#pragma unroll
            for (int j = 0; j < 2; ++j)
                acc[i][j] = __builtin_amdgcn_mfma_f32_16x16x32_bf16(af[i], bfr[j], acc[i][j], 0, 0, 0);
    }

    // epilogue: out[m][n] = acc + b1[n] + Z[label[m]][n]
    int zrow[2][4];
#pragma unroll
    for (int i = 0; i < 2; ++i)
#pragma unroll
        for (int r = 0; r < 4; ++r)
            zrow[i][r] = label[bm + wm + i * 16 + quad * 4 + r] * D_OUT;

#pragma unroll
    for (int j = 0; j < 2; ++j) {
        const int n = bn + wn + j * 16 + l16;
        const float bias = b1[n];
#pragma unroll
        for (int i = 0; i < 2; ++i)
#pragma unroll
            for (int r = 0; r < 4; ++r) {
                const int m = bm + wm + i * 16 + quad * 4 + r;
                out[(size_t)m * D_OUT + n] = acc[i][j][r] + bias + Z[zrow[i][r] + n];
            }
    }
}

// ---------------- launcher ----------------
extern "C" void kernel_launch(void* const* d_in, const int* in_sizes, int n_in,
                              void* d_out, int out_size, void* d_ws, size_t ws_size,
                              hipStream_t stream) {
    const float* x    = (const float*)d_in[0];
    const int*   lab  = (const int*)d_in[1];
    const float* W1_w = (const float*)d_in[2];
    const float* W1_b = (const float*)d_in[3];
    const float* W2_w = (const float*)d_in[4];
    const float* W2_b = (const float*)d_in[5];
    float* out = (float*)d_out;

    char* ws = (char*)d_ws;
    float* s   = (float*)(ws + OFF_S);
    float* Z   = (float*)(ws + OFF_Z);
    float* T   = (float*)(ws + OFF_T);
    int* cnt     = (int*)(ws + OFF_CNT);
    int* offs    = (int*)(ws + OFF_OFFS);
    int* rowlist = (int*)(ws + OFF_ROWL);

    // 1. fused label pipeline (also zeroes T)
    label_kernel<<<1, 1024, 0, stream>>>(lab, T, cnt, offs, rowlist);
    // 2. per-class fp32 sums
    segsum_kernel<<<CPAD, 256, 0, stream>>>(x, offs, cnt, rowlist, s);
    // 3. grand total (64 blocks, 64-way contention only)
    tsum_kernel<<<64, 256, 0, stream>>>(s, T);
    // 4. Z table (inline W2 convert, prefetched)
    dim3 zgrid(CPAD / 64, D_OUT / 64);
    meanz_kernel<<<zgrid, 256, 0, stream>>>(s, T, cnt, W2_w, W2_b, Z);
    // 5. main GEMM (inline W1 convert, prefetched, fused bias + Z gather)
    dim3 ggrid(B / 64, D_OUT / 64);
    gemm1_kernel<<<ggrid, 256, 0, stream>>>(x, W1_w, W1_b, Z, lab, out);
}

// Round 7
// 164.621 us; speedup vs baseline: 1.1748x; 1.1724x over previous
//
#include <hip/hip_runtime.h>
#include <hip/hip_bf16.h>

// Problem constants
constexpr int B      = 16384;
constexpr int D_IN   = 1024;
constexpr int D_OUT  = 256;
constexpr int NCLS   = 1000;
constexpr int CPAD   = 1024;   // padded class count

// ---------------- workspace layout (byte offsets) ----------------
constexpr size_t OFF_XB   = 0;                                    // B*D_IN bf16   (32 MB)
constexpr size_t OFF_WB   = OFF_XB  + (size_t)B * D_IN * 2;       // 512*D_IN bf16 (1 MB)
constexpr size_t OFF_S    = OFF_WB  + (size_t)512 * D_IN * 2;     // CPAD*D_IN f32 (4 MB)
constexpr size_t OFF_Z    = OFF_S   + (size_t)CPAD * D_IN * 4;    // CPAD*D_OUT f32 (1 MB, zeroed)
constexpr size_t OFF_T    = OFF_Z   + (size_t)CPAD * D_OUT * 4;   // D_IN f32 (zeroed)
constexpr size_t OFF_CNT  = OFF_T   + (size_t)D_IN * 4;           // CPAD int (zeroed)
constexpr size_t OFF_OFFS = OFF_CNT + (size_t)CPAD * 4;           // CPAD int
constexpr size_t OFF_CUR  = OFF_OFFS+ (size_t)CPAD * 4;           // CPAD int
constexpr size_t OFF_ROWL = OFF_CUR + (size_t)CPAD * 4;           // B int

typedef short bf16x8 __attribute__((ext_vector_type(8)));
typedef float f32x4  __attribute__((ext_vector_type(4)));

// fp32 -> bf16 round-to-nearest-even
__device__ __forceinline__ unsigned short f2bf(float f) {
    unsigned int u = __float_as_uint(f);
    return (unsigned short)((u + 0x7FFFu + ((u >> 16) & 1u)) >> 16);
}

__device__ __forceinline__ void cvt8(const float4& a, const float4& b, unsigned short* dst) {
    union { unsigned short u[8]; bf16x8 v; } r;
    r.u[0] = f2bf(a.x); r.u[1] = f2bf(a.y); r.u[2] = f2bf(a.z); r.u[3] = f2bf(a.w);
    r.u[4] = f2bf(b.x); r.u[5] = f2bf(b.y); r.u[6] = f2bf(b.z); r.u[7] = f2bf(b.w);
    *(bf16x8*)dst = r.v;
}

__device__ __forceinline__ ushort4 f2bf4(const float4& a) {
    ushort4 r;
    r.x = f2bf(a.x); r.y = f2bf(a.y); r.z = f2bf(a.z); r.w = f2bf(a.w);
    return r;
}

// async global->LDS, 16B/lane; lds dst = wave-uniform base (+lane*16 implied by HW)
__device__ __forceinline__ void async16(const unsigned short* g, unsigned short* l) {
    __builtin_amdgcn_global_load_lds(
        (const __attribute__((address_space(1))) void*)g,
        (__attribute__((address_space(3))) void*)l,
        16, 0, 0);
}

// ---- 1. convert W1,W2 -> Wb bf16; zero cnt, T, Z (256 blocks) ----
__global__ void cvtw_zero_kernel(const float* __restrict__ W1, const float* __restrict__ W2,
                                 unsigned short* __restrict__ Wb,
                                 int* __restrict__ cnt, float* __restrict__ T,
                                 float* __restrict__ Z) {
    int lin = blockIdx.x * blockDim.x + threadIdx.x;   // 0..65535
    int i = lin * 8;
    const float* src = (i < D_OUT * D_IN) ? (W1 + i) : (W2 + (i - D_OUT * D_IN));
    float4 a = *(const float4*)(src);
    float4 b = *(const float4*)(src + 4);
    cvt8(a, b, Wb + i);
    if (lin < CPAD) { cnt[lin] = 0; T[lin] = 0.f; }
    *(float4*)(Z + (size_t)lin * 4) = float4{0.f, 0.f, 0.f, 0.f};   // 65536*4 = 256K floats
}

// ---- 2. histogram (64 blocks) ----
__global__ void hist_kernel(const int* __restrict__ label, int* __restrict__ cnt) {
    int i = blockIdx.x * blockDim.x + threadIdx.x;
    atomicAdd(&cnt[label[i]], 1);
}

// ---- 3. exclusive scan -> offs, cursor (1 block) ----
__global__ __launch_bounds__(1024)
void scan_kernel(const int* __restrict__ cnt, int* __restrict__ offs, int* __restrict__ cursor) {
    __shared__ int bufA[1024];
    __shared__ int bufB[1024];
    int t = threadIdx.x;
    int v = cnt[t];
    bufA[t] = v;
    __syncthreads();
    int* src = bufA;
    int* dst = bufB;
    for (int off = 1; off < 1024; off <<= 1) {
        int sv = src[t];
        if (t >= off) sv += src[t - off];
        dst[t] = sv;
        __syncthreads();
        int* tmp = src; src = dst; dst = tmp;
    }
    int excl = src[t] - v;
    offs[t] = excl;
    cursor[t] = excl;
}

// ---- 4. counting-sort scatter (64 blocks) ----
__global__ void scatter_kernel(const int* __restrict__ label,
                               int* __restrict__ cursor,
                               int* __restrict__ rowlist) {
    int i = blockIdx.x * blockDim.x + threadIdx.x;
    int c = label[i];
    int p = atomicAdd(&cursor[c], 1);
    rowlist[p] = i;
}

// ---- 5. per-class fp32 column sums of x; also emits xb = bf16(x) (1024 blocks) ----
__global__ void segsum_kernel(const float* __restrict__ x,
                              const int* __restrict__ offs,
                              const int* __restrict__ cnt,
                              const int* __restrict__ rowlist,
                              float* __restrict__ s,
                              unsigned short* __restrict__ xb) {
    int c = blockIdx.x;            // 0..1023
    int col = threadIdx.x * 4;
    float4 acc = {0.f, 0.f, 0.f, 0.f};
    if (c < NCLS) {
        int o = offs[c], n = cnt[c];
        int r = 0;
        for (; r + 4 <= n; r += 4) {
            int i0 = rowlist[o + r + 0];
            int i1 = rowlist[o + r + 1];
            int i2 = rowlist[o + r + 2];
            int i3 = rowlist[o + r + 3];
            float4 v0 = *(const float4*)(x + (size_t)i0 * D_IN + col);
            float4 v1 = *(const float4*)(x + (size_t)i1 * D_IN + col);
            float4 v2 = *(const float4*)(x + (size_t)i2 * D_IN + col);
            float4 v3 = *(const float4*)(x + (size_t)i3 * D_IN + col);
            *(ushort4*)(xb + (size_t)i0 * D_IN + col) = f2bf4(v0);
            *(ushort4*)(xb + (size_t)i1 * D_IN + col) = f2bf4(v1);
            *(ushort4*)(xb + (size_t)i2 * D_IN + col) = f2bf4(v2);
            *(ushort4*)(xb + (size_t)i3 * D_IN + col) = f2bf4(v3);
            acc.x += (v0.x + v1.x) + (v2.x + v3.x);
            acc.y += (v0.y + v1.y) + (v2.y + v3.y);
            acc.z += (v0.z + v1.z) + (v2.z + v3.z);
            acc.w += (v0.w + v1.w) + (v2.w + v3.w);
        }
        for (; r < n; ++r) {
            int i0 = rowlist[o + r];
            float4 v = *(const float4*)(x + (size_t)i0 * D_IN + col);
            *(ushort4*)(xb + (size_t)i0 * D_IN + col) = f2bf4(v);
            acc.x += v.x; acc.y += v.y; acc.z += v.z; acc.w += v.w;
        }
    }
    *(float4*)(s + (size_t)c * D_IN + col) = acc;
}

// ---- 6. T = column-sum of s (64 blocks, 64 atomics/address) ----
__global__ void tsum_kernel(const float* __restrict__ s, float* __restrict__ T) {
    int col = threadIdx.x * 4;
    int c0 = blockIdx.x * 16;
    float4 acc = {0.f, 0.f, 0.f, 0.f};
#pragma unroll 4
    for (int c = 0; c < 16; ++c) {
        float4 v = *(const float4*)(s + (size_t)(c0 + c) * D_IN + col);
        acc.x += v.x; acc.y += v.y; acc.z += v.z; acc.w += v.w;
    }
    atomicAdd(&T[col + 0], acc.x);
    atomicAdd(&T[col + 1], acc.y);
    atomicAdd(&T[col + 2], acc.z);
    atomicAdd(&T[col + 3], acc.w);
}

// ---- 7. Z[c] += ((T - s_c)/d_c) @ W2^T (+ b2 in chunk 0); 64x64 tile, K-split x4 ----
__global__ __launch_bounds__(256)
void meanz_kernel(const float* __restrict__ s,
                  const float* __restrict__ T,
                  const int* __restrict__ cnt,
                  const unsigned short* __restrict__ Wb,
                  const float* __restrict__ b2,
                  float* __restrict__ Z) {
    __shared__ unsigned short As[64 * 32];
    __shared__ unsigned short Bs[64 * 32];

    const int tid  = threadIdx.x;
    const int wave = tid >> 6;
    const int lane = tid & 63;
    const int quad = lane >> 4;
    const int l16  = lane & 15;
    const int bm   = blockIdx.x * 64;   // class base
    const int bn   = blockIdx.y * 64;   // out-col base
    const int kb   = blockIdx.z * 256;  // K chunk
    const int wm   = (wave >> 1) * 32;
    const int wn   = (wave & 1) * 32;

    const int arow = tid >> 2;          // 0..63
    const int akc  = (tid & 3) * 8;     // 0,8,16,24

    const int cls = bm + arow;
    const int d   = B - cnt[cls];
    const float scale = (d > 0) ? 1.f / (float)d : 0.f;
    const float* sp = s + (size_t)cls * D_IN + akc;
    const float* tp = T + akc;

    // B async chunk mapping: 1 chunk of 16B per thread
    const int bidx = wave * 64 + lane;
    const int brow = bidx >> 2;
    const int bkc  = (bidx & 3) * 8;
    const unsigned short* bp = Wb + (size_t)(256 + bn + brow) * D_IN + bkc;

    f32x4 acc[2][2] = {};

    for (int k0 = kb; k0 < kb + 256; k0 += 32) {
        float4 s0 = *(const float4*)(sp + k0);
        float4 s1 = *(const float4*)(sp + k0 + 4);
        float4 t0 = *(const float4*)(tp + k0);
        float4 t1 = *(const float4*)(tp + k0 + 4);
        __syncthreads();   // previous iteration's frag reads complete
        async16(bp + k0, Bs + wave * 512);
        float4 m0 = {(t0.x - s0.x) * scale, (t0.y - s0.y) * scale,
                     (t0.z - s0.z) * scale, (t0.w - s0.w) * scale};
        float4 m1 = {(t1.x - s1.x) * scale, (t1.y - s1.y) * scale,
                     (t1.z - s1.z) * scale, (t1.w - s1.w) * scale};
        cvt8(m0, m1, As + arow * 32 + akc);
        __syncthreads();   // drains vmcnt (async B) + lgkm (A writes)

        bf16x8 af[2], bfr[2];
#pragma unroll
        for (int t = 0; t < 2; ++t) {
            af[t]  = *(const bf16x8*)&As[(wm + t * 16 + l16) * 32 + quad * 8];
            bfr[t] = *(const bf16x8*)&Bs[(wn + t * 16 + l16) * 32 + quad * 8];
        }
#pragma unroll
        for (int i = 0; i < 2; ++i)
#pragma unroll
            for (int j = 0; j < 2; ++j)
                acc[i][j] = __builtin_amdgcn_mfma_f32_16x16x32_bf16(af[i], bfr[j], acc[i][j], 0, 0, 0);
    }

    const bool addb = (blockIdx.z == 0);
#pragma unroll
    for (int j = 0; j < 2; ++j) {
        const int n = bn + wn + j * 16 + l16;
        const float bias = addb ? b2[n] : 0.f;
#pragma unroll
        for (int i = 0; i < 2; ++i)
#pragma unroll
            for (int r = 0; r < 4; ++r) {
                const int c = bm + wm + i * 16 + quad * 4 + r;
                atomicAdd(&Z[(size_t)c * D_OUT + n], acc[i][j][r] + bias);
            }
    }
}

// ---- 8. out = xb @ W1b^T + b1 + Z[label] ; 64x64 tile, BK=32, all-async staging ----
__global__ __launch_bounds__(256)
void gemm1_kernel(const unsigned short* __restrict__ xb,
                  const unsigned short* __restrict__ Wb,
                  const float* __restrict__ b1,
                  const float* __restrict__ Z,
                  const int* __restrict__ label,
                  float* __restrict__ out) {
    __shared__ unsigned short As[64 * 32];
    __shared__ unsigned short Bs[64 * 32];

    const int tid  = threadIdx.x;
    const int wave = tid >> 6;
    const int lane = tid & 63;
    const int quad = lane >> 4;
    const int l16  = lane & 15;
    const int bm   = blockIdx.x * 64;
    const int bn   = blockIdx.y * 64;
    const int wm   = (wave >> 1) * 32;
    const int wn   = (wave & 1) * 32;

    // async chunk mapping: 1 chunk of 16B per thread per tile
    const int idx = wave * 64 + lane;
    const int row = idx >> 2;
    const int kc  = (idx & 3) * 8;
    const unsigned short* ap = xb + (size_t)(bm + row) * D_IN + kc;
    const unsigned short* bp = Wb + (size_t)(bn + row) * D_IN + kc;

    f32x4 acc[2][2] = {};

    for (int k0 = 0; k0 < D_IN; k0 += 32) {
        __syncthreads();   // previous iteration's frag reads complete
        async16(ap + k0, As + wave * 512);
        async16(bp + k0, Bs + wave * 512);
        __syncthreads();   // vmcnt drain before frag reads

        bf16x8 af[2], bfr[2];
#pragma unroll
        for (int t = 0; t < 2; ++t) {
            af[t]  = *(const bf16x8*)&As[(wm + t * 16 + l16) * 32 + quad * 8];
            bfr[t] = *(const bf16x8*)&Bs[(wn + t * 16 + l16) * 32 + quad * 8];
        }
#pragma unroll
        for (int i = 0; i < 2; ++i)
#pragma unroll
            for (int j = 0; j < 2; ++j)
                acc[i][j] = __builtin_amdgcn_mfma_f32_16x16x32_bf16(af[i], bfr[j], acc[i][j], 0, 0, 0);
    }

    // epilogue: out[m][n] = acc + b1[n] + Z[label[m]][n]
    int zrow[2][4];
#pragma unroll
    for (int i = 0; i < 2; ++i)
#pragma unroll
        for (int r = 0; r < 4; ++r)
            zrow[i][r] = label[bm + wm + i * 16 + quad * 4 + r] * D_OUT;

#pragma unroll
    for (int j = 0; j < 2; ++j) {
        const int n = bn + wn + j * 16 + l16;
        const float bias = b1[n];
#pragma unroll
        for (int i = 0; i < 2; ++i)
#pragma unroll
            for (int r = 0; r < 4; ++r) {
                const int m = bm + wm + i * 16 + quad * 4 + r;
                out[(size_t)m * D_OUT + n] = acc[i][j][r] + bias + Z[zrow[i][r] + n];
            }
    }
}

// ---------------- launcher ----------------
extern "C" void kernel_launch(void* const* d_in, const int* in_sizes, int n_in,
                              void* d_out, int out_size, void* d_ws, size_t ws_size,
                              hipStream_t stream) {
    const float* x    = (const float*)d_in[0];
    const int*   lab  = (const int*)d_in[1];
    const float* W1_w = (const float*)d_in[2];
    const float* W1_b = (const float*)d_in[3];
    const float* W2_w = (const float*)d_in[4];
    const float* W2_b = (const float*)d_in[5];
    float* out = (float*)d_out;

    char* ws = (char*)d_ws;
    unsigned short* xb = (unsigned short*)(ws + OFF_XB);
    unsigned short* Wb = (unsigned short*)(ws + OFF_WB);
    float* s   = (float*)(ws + OFF_S);
    float* Z   = (float*)(ws + OFF_Z);
    float* T   = (float*)(ws + OFF_T);
    int* cnt     = (int*)(ws + OFF_CNT);
    int* offs    = (int*)(ws + OFF_OFFS);
    int* cursor  = (int*)(ws + OFF_CUR);
    int* rowlist = (int*)(ws + OFF_ROWL);

    // 1. Wb convert + zero cnt/T/Z
    cvtw_zero_kernel<<<256, 256, 0, stream>>>(W1_w, W2_w, Wb, cnt, T, Z);
    // 2. histogram
    hist_kernel<<<64, 256, 0, stream>>>(lab, cnt);
    // 3. scan -> offs, cursor
    scan_kernel<<<1, 1024, 0, stream>>>(cnt, offs, cursor);
    // 4. counting-sort scatter
    scatter_kernel<<<64, 256, 0, stream>>>(lab, cursor, rowlist);
    // 5. per-class sums + xb emit
    segsum_kernel<<<CPAD, 256, 0, stream>>>(x, offs, cnt, rowlist, s, xb);
    // 6. grand total
    tsum_kernel<<<64, 256, 0, stream>>>(s, T);
    // 7. Z table (K-split x4, 256 blocks)
    dim3 zgrid(CPAD / 64, D_OUT / 64, 4);
    meanz_kernel<<<zgrid, 256, 0, stream>>>(s, T, cnt, Wb, W2_b, Z);
    // 8. main GEMM, pure-bf16 async staging
    dim3 ggrid(B / 64, D_OUT / 64);
    gemm1_kernel<<<ggrid, 256, 0, stream>>>(xb, Wb, W1_b, Z, lab, out);
}